// Round 1
// baseline (1445.026 us; speedup 1.0000x reference)
//
#include <hip/hip_runtime.h>
#include <math.h>

#define L_    9216
#define WIN   144
#define NWIN  64
#define KJ    432

// ---------------- weight pre-transpose for conv3x3 ----------------
// wtr[(c*9+kk)*64 + cq] = wm[cq*2304 + c*9 + kk]
__global__ void k_wprep(const float* __restrict__ wm, float* __restrict__ wtr) {
    int s = blockIdx.x * 256 + threadIdx.x;       // 147456 total
    if (s < 147456) {
        int cq = s & 63, r = s >> 6;              // r = c*9+kk
        wtr[s] = wm[(size_t)cq * 2304 + r];
    }
}

// ---------------- conv3x3: x[8,256,96,96] -> xe[8,9216,64] ----------------
// grid 768 (n*96+h), block 128. thread tile: 4 cq x 12 w.
__global__ __launch_bounds__(128) void k_conv3x3(const float* __restrict__ x,
                                                 const float* __restrict__ wtr,
                                                 const float* __restrict__ bm,
                                                 float* __restrict__ xe) {
    __shared__ float srow[3][100];
    __shared__ float sw[576];
    __shared__ float sout[96 * 64];
    const int n = blockIdx.x / 96, h = blockIdx.x % 96;
    const int t = threadIdx.x;
    const int cg = t >> 3, wg = t & 7;           // cq0 = cg*4, w0 = wg*12
    const int cq0 = cg * 4, w0 = wg * 12;
    float acc[12][4];
#pragma unroll
    for (int j = 0; j < 12; j++)
#pragma unroll
        for (int q = 0; q < 4; q++) acc[j][q] = 0.f;

    for (int c = 0; c < 256; c++) {
        __syncthreads();
        for (int s = t; s < 3 * 98; s += 128) {
            int dh = s / 98, ww = s % 98;
            int hh = h + dh - 1, wx = ww - 1;
            float v = 0.f;
            if (hh >= 0 && hh < 96 && wx >= 0 && wx < 96)
                v = x[((size_t)(n * 256 + c) * 96 + hh) * 96 + wx];
            srow[dh][ww] = v;
        }
        for (int s = t; s < 576; s += 128) sw[s] = wtr[(size_t)c * 576 + s];
        __syncthreads();

        float xv[3][16];
#pragma unroll
        for (int dh = 0; dh < 3; dh++)
#pragma unroll
            for (int q = 0; q < 4; q++) {
                float4 t4 = *(const float4*)(&srow[dh][w0 + q * 4]);
                xv[dh][q * 4 + 0] = t4.x; xv[dh][q * 4 + 1] = t4.y;
                xv[dh][q * 4 + 2] = t4.z; xv[dh][q * 4 + 3] = t4.w;
            }
#pragma unroll
        for (int dh = 0; dh < 3; dh++)
#pragma unroll
            for (int kw = 0; kw < 3; kw++) {
                const float4 wq = *(const float4*)(&sw[(dh * 3 + kw) * 64 + cq0]);
#pragma unroll
                for (int j = 0; j < 12; j++) {
                    const float xvv = xv[dh][j + kw];
                    acc[j][0] += xvv * wq.x; acc[j][1] += xvv * wq.y;
                    acc[j][2] += xvv * wq.z; acc[j][3] += xvv * wq.w;
                }
            }
    }
    __syncthreads();
    const float b0 = bm[cq0], b1 = bm[cq0 + 1], b2 = bm[cq0 + 2], b3 = bm[cq0 + 3];
#pragma unroll
    for (int j = 0; j < 12; j++) {
        sout[(w0 + j) * 64 + cq0 + 0] = acc[j][0] + b0;
        sout[(w0 + j) * 64 + cq0 + 1] = acc[j][1] + b1;
        sout[(w0 + j) * 64 + cq0 + 2] = acc[j][2] + b2;
        sout[(w0 + j) * 64 + cq0 + 3] = acc[j][3] + b3;
    }
    __syncthreads();
    float4* dst = (float4*)(xe + ((size_t)n * L_ + (size_t)h * 96) * 64);
    const float4* src = (const float4*)sout;
    for (int s = t; s < 96 * 16; s += 128) dst[s] = src[s];
}

// ---------------- conv1x1: ye[8,9216,256] ----------------
// grid 1152 (n*144+lt), block 256; tile 64 l x 256 co; thread 8l x 8co.
__global__ __launch_bounds__(256) void k_conv1x1(const float* __restrict__ x,
                                                 const float* __restrict__ wa,
                                                 const float* __restrict__ ba,
                                                 float* __restrict__ ye) {
    __shared__ float sx[32 * 64];
    __shared__ float swt[32 * 260];
    const int n = blockIdx.x / 144, lt = blockIdx.x % 144;
    const int l0 = lt * 64;
    const int t = threadIdx.x;
    const int cg = t & 31, lg = t >> 5;   // co = cg*8.., l = lg*8..
    float acc[8][8];
#pragma unroll
    for (int li = 0; li < 8; li++)
#pragma unroll
        for (int ci = 0; ci < 8; ci++) acc[li][ci] = 0.f;

    for (int ct = 0; ct < 8; ct++) {
        __syncthreads();
        for (int s = t; s < 2048; s += 256) {
            int cc = s >> 6, ll = s & 63;
            sx[cc * 64 + ll] = x[((size_t)(n * 256) + ct * 32 + cc) * L_ + l0 + ll];
        }
        for (int s = t; s < 8192; s += 256) {
            int co = s >> 5, cc = s & 31;
            swt[cc * 260 + co] = wa[(size_t)co * 256 + ct * 32 + cc];
        }
        __syncthreads();
#pragma unroll 8
        for (int cc = 0; cc < 32; cc++) {
            float4 xa4 = *(const float4*)(sx + cc * 64 + lg * 8);
            float4 xb4 = *(const float4*)(sx + cc * 64 + lg * 8 + 4);
            float4 wa4 = *(const float4*)(swt + cc * 260 + cg * 8);
            float4 wb4 = *(const float4*)(swt + cc * 260 + cg * 8 + 4);
            float xs[8] = {xa4.x, xa4.y, xa4.z, xa4.w, xb4.x, xb4.y, xb4.z, xb4.w};
            float ws_[8] = {wa4.x, wa4.y, wa4.z, wa4.w, wb4.x, wb4.y, wb4.z, wb4.w};
#pragma unroll
            for (int li = 0; li < 8; li++)
#pragma unroll
                for (int ci = 0; ci < 8; ci++) acc[li][ci] += xs[li] * ws_[ci];
        }
    }
    float bias[8];
#pragma unroll
    for (int ci = 0; ci < 8; ci++) bias[ci] = ba[cg * 8 + ci];
#pragma unroll
    for (int li = 0; li < 8; li++) {
        int l = l0 + lg * 8 + li;
        float4 o0, o1;
        o0.x = acc[li][0] + bias[0]; o0.y = acc[li][1] + bias[1];
        o0.z = acc[li][2] + bias[2]; o0.w = acc[li][3] + bias[3];
        o1.x = acc[li][4] + bias[4]; o1.y = acc[li][5] + bias[5];
        o1.z = acc[li][6] + bias[6]; o1.w = acc[li][7] + bias[7];
        *(float4*)(ye + ((size_t)n * L_ + l) * 256 + cg * 8) = o0;
        *(float4*)(ye + ((size_t)n * L_ + l) * 256 + cg * 8 + 4) = o1;
    }
}

// ---------------- kmeans assign (fp64 dot; norm is argmax-invariant) ----------------
__global__ __launch_bounds__(256) void k_assign(const float* __restrict__ xe,
                                                const float* __restrict__ means,
                                                int* __restrict__ codes_i,
                                                float* __restrict__ codes_f) {
    __shared__ float sm[128 * 64];
    for (int s = threadIdx.x; s < 8192; s += 256) sm[s] = means[s];
    __syncthreads();
    const int g = blockIdx.x * 256 + threadIdx.x;
    const float* row = xe + (size_t)g * 64;
    float v[64];
#pragma unroll
    for (int c4 = 0; c4 < 16; c4++) {
        float4 t4 = *(const float4*)(row + c4 * 4);
        v[c4 * 4 + 0] = t4.x; v[c4 * 4 + 1] = t4.y; v[c4 * 4 + 2] = t4.z; v[c4 * 4 + 3] = t4.w;
    }
    int best = 0;
    double bd = -1e300;
    for (int cl = 0; cl < 128; cl++) {
        double d = 0.0;
#pragma unroll
        for (int c4 = 0; c4 < 16; c4++) {
            float4 m4 = *(const float4*)(sm + cl * 64 + c4 * 4);
            d += (double)v[c4 * 4 + 0] * (double)m4.x + (double)v[c4 * 4 + 1] * (double)m4.y +
                 (double)v[c4 * 4 + 2] * (double)m4.z + (double)v[c4 * 4 + 3] * (double)m4.w;
        }
        if (d > bd) { bd = d; best = cl; }
    }
    codes_i[g] = best;
    codes_f[g] = (float)best;
}

// ---------------- stable counting sort (matches jnp.argsort stable) ----------------
__global__ void k_hist(const int* __restrict__ codes_i, int* __restrict__ hist) {
    __shared__ int h[128];
    if (threadIdx.x < 128) h[threadIdx.x] = 0;
    __syncthreads();
    int n = blockIdx.x / 36, ch = blockIdx.x % 36;
    int c = codes_i[n * L_ + ch * 256 + threadIdx.x];
    atomicAdd(&h[c], 1);
    __syncthreads();
    if (threadIdx.x < 128) hist[(n * 36 + ch) * 128 + threadIdx.x] = h[threadIdx.x];
}

__global__ void k_scan(const int* __restrict__ hist, int* __restrict__ basebuf) {
    __shared__ int tot[128];
    __shared__ int binstart[128];
    int n = blockIdx.x, c = threadIdx.x;
    int run = 0;
    int local[36];
    for (int ch = 0; ch < 36; ch++) { local[ch] = run; run += hist[(n * 36 + ch) * 128 + c]; }
    tot[c] = run;
    __syncthreads();
    if (c == 0) {
        int s = 0;
        for (int b = 0; b < 128; b++) { binstart[b] = s; s += tot[b]; }
    }
    __syncthreads();
    int bs0 = binstart[c];
    for (int ch = 0; ch < 36; ch++) basebuf[(n * 36 + ch) * 128 + c] = bs0 + local[ch];
}

__global__ void k_rank(const int* __restrict__ codes_i, const int* __restrict__ basebuf,
                       int* __restrict__ idxb, int* __restrict__ undo) {
    __shared__ int sc[256];
    __shared__ int sb[128];
    int n = blockIdx.x / 36, ch = blockIdx.x % 36;
    int i = threadIdx.x;
    int l = ch * 256 + i;
    int c = codes_i[n * L_ + l];
    sc[i] = c;
    if (i < 128) sb[i] = basebuf[(n * 36 + ch) * 128 + i];
    __syncthreads();
    int r = 0;
    for (int j = 0; j < i; j++) r += (sc[j] == c);
    int pos = sb[c] + r;
    idxb[n * L_ + pos] = l;
    undo[n * L_ + l] = pos;
}

// ---------------- QK: raw logits -> score region ----------------
// grid 1024 ((n*64+k)*2+ih), block 128 (8 ti x 16 tj); thread 9x9 tile.
__global__ __launch_bounds__(128) void k_qk(const float* __restrict__ xe,
                                            const int* __restrict__ idxb,
                                            float* __restrict__ raw) {
    __shared__ float sq[72 * 68];
    __shared__ float sk[10368];     // 144 key rows @ stride 68; reused as 72x144 dump
    __shared__ int sidx[432];
    const int bid = blockIdx.x;
    const int n = bid >> 7, k = (bid >> 1) & 63, ih = bid & 1;
    const int t = threadIdx.x;
    const int ti = t >> 4, tj = t & 15;

    for (int s = t; s < 432; s += 128) {
        int wb = s / 144, jj = s % 144;
        int wk = (wb == 0) ? k : (wb == 1) ? ((k + 63) & 63) : ((k + 1) & 63);
        sidx[s] = idxb[n * L_ + wk * WIN + jj];
    }
    __syncthreads();
    for (int s = t; s < 72 * 16; s += 128) {
        int rr = s >> 4, q4 = s & 15;
        int l = sidx[ih * 72 + rr];
        *(float4*)(sq + rr * 68 + q4 * 4) = *(const float4*)(xe + ((size_t)n * L_ + l) * 64 + q4 * 4);
    }
    float* outbase = raw + (size_t)(n * NWIN + k) * WIN * KJ + (size_t)ih * 72 * KJ;

    for (int wb = 0; wb < 3; wb++) {
        __syncthreads();
        for (int s = t; s < 144 * 16; s += 128) {
            int rr = s >> 4, q4 = s & 15;
            int l = sidx[wb * 144 + rr];
            float4 v = *(const float4*)(xe + ((size_t)n * L_ + l) * 64 + q4 * 4);
            float ss = v.x * v.x + v.y * v.y + v.z * v.z + v.w * v.w;
            ss += __shfl_xor(ss, 1); ss += __shfl_xor(ss, 2);
            ss += __shfl_xor(ss, 4); ss += __shfl_xor(ss, 8);
            float inv = 1.0f / fmaxf(sqrtf(ss), 5e-5f);
            v.x *= inv; v.y *= inv; v.z *= inv; v.w *= inv;
            *(float4*)(sk + rr * 68 + q4 * 4) = v;
        }
        __syncthreads();
        float acc[9][9];
#pragma unroll
        for (int a = 0; a < 9; a++)
#pragma unroll
            for (int b = 0; b < 9; b++) acc[a][b] = 0.f;
        for (int c4 = 0; c4 < 16; c4++) {
            float4 qv[9], kv[9];
#pragma unroll
            for (int a = 0; a < 9; a++) qv[a] = *(const float4*)(sq + (ti * 9 + a) * 68 + c4 * 4);
#pragma unroll
            for (int b = 0; b < 9; b++) kv[b] = *(const float4*)(sk + (tj * 9 + b) * 68 + c4 * 4);
#pragma unroll
            for (int a = 0; a < 9; a++)
#pragma unroll
                for (int b = 0; b < 9; b++)
                    acc[a][b] += qv[a].x * kv[b].x + qv[a].y * kv[b].y +
                                 qv[a].z * kv[b].z + qv[a].w * kv[b].w;
        }
        __syncthreads();      // done reading sk keys
#pragma unroll
        for (int a = 0; a < 9; a++)
#pragma unroll
            for (int b = 0; b < 9; b++)
                sk[(ti * 9 + a) * 144 + tj * 9 + b] = acc[a][b];
        __syncthreads();
        for (int s = t; s < 72 * 36; s += 128) {
            int i = s / 36, q = s % 36;
            *(float4*)(outbase + (size_t)i * KJ + wb * 144 + q * 4) =
                *(const float4*)(sk + i * 144 + q * 4);
        }
    }
}

// ---------------- row softmax in place + bs ----------------
__global__ __launch_bounds__(256) void k_softmax(float* __restrict__ score, float* __restrict__ bs) {
    const int row = blockIdx.x * 4 + (threadIdx.x >> 6);
    const int lane = threadIdx.x & 63;
    float* p = score + (size_t)row * KJ;
    float v[7];
    float m = -1e30f;
#pragma unroll
    for (int it = 0; it < 7; it++) {
        int j = lane + it * 64;
        v[it] = (j < KJ) ? p[j] : -1e30f;
        m = fmaxf(m, v[it]);
    }
#pragma unroll
    for (int o = 32; o >= 1; o >>= 1) m = fmaxf(m, __shfl_xor(m, o));
    float s = 0.f;
#pragma unroll
    for (int it = 0; it < 7; it++) {
        v[it] = __expf(v[it] - m);
        s += (lane + it * 64 < KJ) ? v[it] : 0.f;
    }
#pragma unroll
    for (int o = 32; o >= 1; o >>= 1) s += __shfl_xor(s, o);
    float inv = 1.f / s;
#pragma unroll
    for (int it = 0; it < 7; it++) {
        int j = lane + it * 64;
        if (j < KJ) p[j] = v[it] * inv;
    }
    if (lane == 0) bs[row] = m + logf(s);
}

// ---------------- PV: ret_sorted = score @ Y3 ----------------
// grid 2048 ((n*64+k)*4+cq4), block 256 (16 ti x 16 tj); thread 9i x 4c.
__global__ __launch_bounds__(256) void k_pv(const float* __restrict__ ye,
                                            const int* __restrict__ idxb,
                                            const float* __restrict__ score,
                                            float* __restrict__ ret) {
    __shared__ float ss[144 * 49];
    __shared__ float sy[48 * 68];
    __shared__ int sidx[432];
    const int bid = blockIdx.x;
    const int n = bid >> 8, k = (bid >> 2) & 63, cqb = (bid & 3) * 64;
    const int t = threadIdx.x;
    const int ti = t >> 4, tj = t & 15;

    for (int s = t; s < 432; s += 256) {
        int wb = s / 144, jj = s % 144;
        int wk = (wb == 0) ? k : (wb == 1) ? ((k + 63) & 63) : ((k + 1) & 63);
        sidx[s] = idxb[n * L_ + wk * WIN + jj];
    }
    float acc[9][4];
#pragma unroll
    for (int a = 0; a < 9; a++)
#pragma unroll
        for (int q = 0; q < 4; q++) acc[a][q] = 0.f;
    const float* srowbase = score + (size_t)(n * NWIN + k) * WIN * KJ;

    for (int jt = 0; jt < 9; jt++) {
        __syncthreads();
        for (int s = t; s < 144 * 48; s += 256) {
            int i = s / 48, jj = s % 48;
            ss[i * 49 + jj] = srowbase[(size_t)i * KJ + jt * 48 + jj];
        }
        for (int s = t; s < 48 * 16; s += 256) {
            int jj = s >> 4, q = s & 15;
            int l = sidx[jt * 48 + jj];
            *(float4*)(sy + jj * 68 + q * 4) =
                *(const float4*)(ye + ((size_t)n * L_ + l) * 256 + cqb + q * 4);
        }
        __syncthreads();
#pragma unroll 4
        for (int jj = 0; jj < 48; jj++) {
            float4 yv = *(const float4*)(sy + jj * 68 + tj * 4);
#pragma unroll
            for (int a = 0; a < 9; a++) {
                float sv = ss[(ti * 9 + a) * 49 + jj];
                acc[a][0] += sv * yv.x; acc[a][1] += sv * yv.y;
                acc[a][2] += sv * yv.z; acc[a][3] += sv * yv.w;
            }
        }
    }
#pragma unroll
    for (int a = 0; a < 9; a++) {
        int i = ti * 9 + a;
        float4 o = {acc[a][0], acc[a][1], acc[a][2], acc[a][3]};
        *(float4*)(ret + ((size_t)n * L_ + (size_t)k * WIN + i) * 256 + cqb + tj * 4) = o;
    }
}

// ---------------- final scatter: out = x + 0.1 * ret[undo] ----------------
// grid 2304 (n*288+lt), block 256; 32 tokens per block.
__global__ __launch_bounds__(256) void k_out(const float* __restrict__ x,
                                             const float* __restrict__ ret,
                                             const int* __restrict__ undo,
                                             float* __restrict__ out) {
    __shared__ float sr[32 * 257];
    const int n = blockIdx.x / 288, lt = blockIdx.x % 288;
    const int lbase = lt * 32;
    const int t = threadIdx.x;
    for (int s = t; s < 32 * 64; s += 256) {
        int lr = s >> 6, q = s & 63;
        int p = undo[n * L_ + lbase + lr];
        *(float4*)(sr + lr * 257 + q * 4) = *(const float4*)(ret + ((size_t)n * L_ + p) * 256 + q * 4);
    }
    __syncthreads();
    const int lr = t & 31, cog = t >> 5;
    for (int cc = 0; cc < 32; cc++) {
        int co = cog * 32 + cc;
        size_t gi = ((size_t)(n * 256 + co)) * L_ + lbase + lr;
        out[gi] = x[gi] + 0.1f * sr[lr * 257 + co];
    }
}

extern "C" void kernel_launch(void* const* d_in, const int* in_sizes, int n_in,
                              void* d_out, int out_size, void* d_ws, size_t ws_size,
                              hipStream_t stream) {
    (void)in_sizes; (void)n_in; (void)out_size; (void)ws_size;
    const float* x     = (const float*)d_in[0];
    const float* means = (const float*)d_in[1];
    const float* wm    = (const float*)d_in[2];
    const float* bm    = (const float*)d_in[3];
    const float* wa    = (const float*)d_in[4];
    const float* ba    = (const float*)d_in[5];

    float* out   = (float*)d_out;
    float* score = out + (size_t)8 * 256 * L_;                 // 18,874,368
    float* bs    = score + (size_t)8 * NWIN * WIN * KJ;        // +31,850,496
    float* codesf = bs + (size_t)8 * L_;                       // +73,728

    float* xe  = (float*)d_ws;                                  // 4,718,592 f
    float* ye  = xe + (size_t)8 * L_ * 64;                      // 18,874,368 f
    float* ret = ye + (size_t)8 * L_ * 256;                     // 18,874,368 f
    float* wtr = ret + (size_t)8 * L_ * 256;                    // 147,456 f
    int* codes_i = (int*)(wtr + 147456);
    int* idxb    = codes_i + 8 * L_;
    int* undo    = idxb + 8 * L_;
    int* hist    = undo + 8 * L_;
    int* basebuf = hist + 8 * 36 * 128;

    k_wprep  <<<576, 256, 0, stream>>>(wm, wtr);
    k_conv3x3<<<768, 128, 0, stream>>>(x, wtr, bm, xe);
    k_conv1x1<<<1152, 256, 0, stream>>>(x, wa, ba, ye);
    k_assign <<<288, 256, 0, stream>>>(xe, means, codes_i, codesf);
    k_hist   <<<288, 256, 0, stream>>>(codes_i, hist);
    k_scan   <<<8, 128, 0, stream>>>(hist, basebuf);
    k_rank   <<<288, 256, 0, stream>>>(codes_i, basebuf, idxb, undo);
    k_qk     <<<1024, 128, 0, stream>>>(xe, idxb, score);
    k_softmax<<<18432, 256, 0, stream>>>(score, bs);
    k_pv     <<<2048, 256, 0, stream>>>(ye, idxb, score, ret);
    k_out    <<<2304, 256, 0, stream>>>(x, ret, undo, out);
}

// Round 2
// 1372.167 us; speedup vs baseline: 1.0531x; 1.0531x over previous
//
#include <hip/hip_runtime.h>
#include <math.h>

#define L_    9216
#define WIN   144
#define NWIN  64
#define KJ    432

// ---------------- weight pre-transpose for conv3x3 ----------------
// wtr[(c*9+kk)*64 + cq] = wm[cq*2304 + c*9 + kk]
__global__ void k_wprep(const float* __restrict__ wm, float* __restrict__ wtr) {
    int s = blockIdx.x * 256 + threadIdx.x;       // 147456 total
    if (s < 147456) {
        int cq = s & 63, r = s >> 6;              // r = c*9+kk
        wtr[s] = wm[(size_t)cq * 2304 + r];
    }
}

// ---------------- conv3x3 v2: x[8,256,96,96] -> xe[8,9216,64] ----------------
// grid 1536 ((n*96+h)*2+half), block 128 (8 wg x 16 cg); thread 12w x 2cq.
// Double-buffered LDS, register-staged loads (issue-early / ds_write-late).
__global__ __launch_bounds__(128) void k_conv3x3(const float* __restrict__ x,
                                                 const float* __restrict__ wtr,
                                                 const float* __restrict__ bm,
                                                 float* __restrict__ xe) {
    __shared__ float sxf[2][624];   // [buf][(ch*3+row)*104 + ww], ww 0..99 (col = ww-1)
    __shared__ float swf[2][576];   // [buf][(ch*9+kk)*32 + cqh]
    const int bid = blockIdx.x;
    const int half = bid & 1, h = (bid >> 1) % 96, n = bid / 192;
    const int t = threadIdx.x;
    const int wg = t >> 4, cg = t & 15;
    const int w0 = wg * 12, cq0 = half * 32 + cg * 2;
    const size_t noff = (size_t)n * 256 * 9216;

    // --- precompute staging descriptors (channel-chunk invariant) ---
    int xdst[5], xsoff[5], xval[5], nx = 0;
    for (int s = t; s < 600; s += 128) {
        int ch = s / 300, rem = s % 300;
        int row = rem / 100, ww = rem % 100;
        int hh = h + row - 1, col = ww - 1;
        int v = (hh >= 0 && hh < 96 && col >= 0 && col < 96 && ww < 98);
        xdst[nx] = (ch * 3 + row) * 104 + ww;
        xsoff[nx] = v ? (ch * 9216 + hh * 96 + col) : 0;
        xval[nx] = v;
        nx++;
    }
    int wdst[5], wsoff[5], nw = 0;
    for (int s = t; s < 576; s += 128) {
        int ch = s / 288, r = s % 288;
        int kk = r >> 5, cqh = r & 31;
        wdst[nw] = (ch * 9 + kk) * 32 + cqh;
        wsoff[nw] = ch * 576 + kk * 64 + half * 32 + cqh;
        nw++;
    }

    float acc[12][2];
#pragma unroll
    for (int j = 0; j < 12; j++) { acc[j][0] = 0.f; acc[j][1] = 0.f; }

    float xr[5], wr[5];
#define CONV_ISSUE(cbase)                                                     \
    do {                                                                      \
        _Pragma("unroll")                                                     \
        for (int k = 0; k < 5; ++k)                                           \
            if (k < nx) xr[k] = xval[k] ? x[noff + (size_t)(cbase) * 9216 + xsoff[k]] : 0.f; \
        _Pragma("unroll")                                                     \
        for (int k = 0; k < 5; ++k)                                           \
            if (k < nw) wr[k] = wtr[(size_t)(cbase) * 576 + wsoff[k]];        \
    } while (0)
#define CONV_COMMIT(buf)                                                      \
    do {                                                                      \
        _Pragma("unroll")                                                     \
        for (int k = 0; k < 5; ++k) if (k < nx) sxf[buf][xdst[k]] = xr[k];    \
        _Pragma("unroll")                                                     \
        for (int k = 0; k < 5; ++k) if (k < nw) swf[buf][wdst[k]] = wr[k];    \
    } while (0)

    CONV_ISSUE(0);
    CONV_COMMIT(0);
    __syncthreads();

    for (int cc = 0; cc < 128; ++cc) {
        const int cur = cc & 1;
        if (cc < 127) CONV_ISSUE((cc + 1) * 2);
        // compute 2 channels from buf[cur]
#pragma unroll
        for (int ch = 0; ch < 2; ++ch) {
            float xv[3][16];
#pragma unroll
            for (int r = 0; r < 3; ++r)
#pragma unroll
                for (int q = 0; q < 4; ++q) {
                    float4 v = *(const float4*)&sxf[cur][(ch * 3 + r) * 104 + w0 + q * 4];
                    xv[r][q * 4 + 0] = v.x; xv[r][q * 4 + 1] = v.y;
                    xv[r][q * 4 + 2] = v.z; xv[r][q * 4 + 3] = v.w;
                }
#pragma unroll
            for (int dh = 0; dh < 3; ++dh)
#pragma unroll
                for (int kw = 0; kw < 3; ++kw) {
                    float2 wv = *(const float2*)&swf[cur][(ch * 9 + dh * 3 + kw) * 32 + cg * 2];
#pragma unroll
                    for (int j = 0; j < 12; ++j) {
                        acc[j][0] += xv[dh][j + kw] * wv.x;
                        acc[j][1] += xv[dh][j + kw] * wv.y;
                    }
                }
        }
        if (cc < 127) CONV_COMMIT(cur ^ 1);
        __syncthreads();
    }

    const float b0 = bm[cq0], b1 = bm[cq0 + 1];
#pragma unroll
    for (int j = 0; j < 12; ++j) {
        float2 o = {acc[j][0] + b0, acc[j][1] + b1};
        *(float2*)&xe[((size_t)n * L_ + (size_t)h * 96 + w0 + j) * 64 + cq0] = o;
    }
#undef CONV_ISSUE
#undef CONV_COMMIT
}

// ---------------- conv1x1: ye[8,9216,256] ----------------
// grid 1152 (n*144+lt), block 256; tile 64 l x 256 co; thread 8l x 8co.
__global__ __launch_bounds__(256) void k_conv1x1(const float* __restrict__ x,
                                                 const float* __restrict__ wa,
                                                 const float* __restrict__ ba,
                                                 float* __restrict__ ye) {
    __shared__ float sx[32 * 64];
    __shared__ float swt[32 * 260];
    const int n = blockIdx.x / 144, lt = blockIdx.x % 144;
    const int l0 = lt * 64;
    const int t = threadIdx.x;
    const int cg = t & 31, lg = t >> 5;   // co = cg*8.., l = lg*8..
    float acc[8][8];
#pragma unroll
    for (int li = 0; li < 8; li++)
#pragma unroll
        for (int ci = 0; ci < 8; ci++) acc[li][ci] = 0.f;

    for (int ct = 0; ct < 8; ct++) {
        __syncthreads();
        for (int s = t; s < 2048; s += 256) {
            int cc = s >> 6, ll = s & 63;
            sx[cc * 64 + ll] = x[((size_t)(n * 256) + ct * 32 + cc) * L_ + l0 + ll];
        }
        for (int s = t; s < 8192; s += 256) {
            int co = s >> 5, cc = s & 31;
            swt[cc * 260 + co] = wa[(size_t)co * 256 + ct * 32 + cc];
        }
        __syncthreads();
#pragma unroll 8
        for (int cc = 0; cc < 32; cc++) {
            float4 xa4 = *(const float4*)(sx + cc * 64 + lg * 8);
            float4 xb4 = *(const float4*)(sx + cc * 64 + lg * 8 + 4);
            float4 wa4 = *(const float4*)(swt + cc * 260 + cg * 8);
            float4 wb4 = *(const float4*)(swt + cc * 260 + cg * 8 + 4);
            float xs[8] = {xa4.x, xa4.y, xa4.z, xa4.w, xb4.x, xb4.y, xb4.z, xb4.w};
            float ws_[8] = {wa4.x, wa4.y, wa4.z, wa4.w, wb4.x, wb4.y, wb4.z, wb4.w};
#pragma unroll
            for (int li = 0; li < 8; li++)
#pragma unroll
                for (int ci = 0; ci < 8; ci++) acc[li][ci] += xs[li] * ws_[ci];
        }
    }
    float bias[8];
#pragma unroll
    for (int ci = 0; ci < 8; ci++) bias[ci] = ba[cg * 8 + ci];
#pragma unroll
    for (int li = 0; li < 8; li++) {
        int l = l0 + lg * 8 + li;
        float4 o0, o1;
        o0.x = acc[li][0] + bias[0]; o0.y = acc[li][1] + bias[1];
        o0.z = acc[li][2] + bias[2]; o0.w = acc[li][3] + bias[3];
        o1.x = acc[li][4] + bias[4]; o1.y = acc[li][5] + bias[5];
        o1.z = acc[li][6] + bias[6]; o1.w = acc[li][7] + bias[7];
        *(float4*)(ye + ((size_t)n * L_ + l) * 256 + cg * 8) = o0;
        *(float4*)(ye + ((size_t)n * L_ + l) * 256 + cg * 8 + 4) = o1;
    }
}

// ---------------- kmeans assign (fp64 dot; norm is argmax-invariant) ----------------
__global__ __launch_bounds__(256) void k_assign(const float* __restrict__ xe,
                                                const float* __restrict__ means,
                                                int* __restrict__ codes_i,
                                                float* __restrict__ codes_f) {
    __shared__ float sm[128 * 64];
    for (int s = threadIdx.x; s < 8192; s += 256) sm[s] = means[s];
    __syncthreads();
    const int g = blockIdx.x * 256 + threadIdx.x;
    const float* row = xe + (size_t)g * 64;
    float v[64];
#pragma unroll
    for (int c4 = 0; c4 < 16; c4++) {
        float4 t4 = *(const float4*)(row + c4 * 4);
        v[c4 * 4 + 0] = t4.x; v[c4 * 4 + 1] = t4.y; v[c4 * 4 + 2] = t4.z; v[c4 * 4 + 3] = t4.w;
    }
    int best = 0;
    double bd = -1e300;
    for (int cl = 0; cl < 128; cl++) {
        double d = 0.0;
#pragma unroll
        for (int c4 = 0; c4 < 16; c4++) {
            float4 m4 = *(const float4*)(sm + cl * 64 + c4 * 4);
            d += (double)v[c4 * 4 + 0] * (double)m4.x + (double)v[c4 * 4 + 1] * (double)m4.y +
                 (double)v[c4 * 4 + 2] * (double)m4.z + (double)v[c4 * 4 + 3] * (double)m4.w;
        }
        if (d > bd) { bd = d; best = cl; }
    }
    codes_i[g] = best;
    codes_f[g] = (float)best;
}

// ---------------- stable counting sort (matches jnp.argsort stable) ----------------
__global__ void k_hist(const int* __restrict__ codes_i, int* __restrict__ hist) {
    __shared__ int h[128];
    if (threadIdx.x < 128) h[threadIdx.x] = 0;
    __syncthreads();
    int n = blockIdx.x / 36, ch = blockIdx.x % 36;
    int c = codes_i[n * L_ + ch * 256 + threadIdx.x];
    atomicAdd(&h[c], 1);
    __syncthreads();
    if (threadIdx.x < 128) hist[(n * 36 + ch) * 128 + threadIdx.x] = h[threadIdx.x];
}

__global__ void k_scan(const int* __restrict__ hist, int* __restrict__ basebuf) {
    __shared__ int tot[128];
    __shared__ int binstart[128];
    int n = blockIdx.x, c = threadIdx.x;
    int run = 0;
    int local[36];
    for (int ch = 0; ch < 36; ch++) { local[ch] = run; run += hist[(n * 36 + ch) * 128 + c]; }
    tot[c] = run;
    __syncthreads();
    if (c == 0) {
        int s = 0;
        for (int b = 0; b < 128; b++) { binstart[b] = s; s += tot[b]; }
    }
    __syncthreads();
    int bs0 = binstart[c];
    for (int ch = 0; ch < 36; ch++) basebuf[(n * 36 + ch) * 128 + c] = bs0 + local[ch];
}

__global__ void k_rank(const int* __restrict__ codes_i, const int* __restrict__ basebuf,
                       int* __restrict__ idxb, int* __restrict__ undo) {
    __shared__ int sc[256];
    __shared__ int sb[128];
    int n = blockIdx.x / 36, ch = blockIdx.x % 36;
    int i = threadIdx.x;
    int l = ch * 256 + i;
    int c = codes_i[n * L_ + l];
    sc[i] = c;
    if (i < 128) sb[i] = basebuf[(n * 36 + ch) * 128 + i];
    __syncthreads();
    int r = 0;
    for (int j = 0; j < i; j++) r += (sc[j] == c);
    int pos = sb[c] + r;
    idxb[n * L_ + pos] = l;
    undo[n * L_ + l] = pos;
}

// ---------------- QK: raw logits -> score region ----------------
// grid 1024 ((n*64+k)*2+ih), block 128 (8 ti x 16 tj); thread 9x9 tile.
__global__ __launch_bounds__(128) void k_qk(const float* __restrict__ xe,
                                            const int* __restrict__ idxb,
                                            float* __restrict__ raw) {
    __shared__ float sq[72 * 68];
    __shared__ float sk[10368];     // 144 key rows @ stride 68; reused as 72x144 dump
    __shared__ int sidx[432];
    const int bid = blockIdx.x;
    const int n = bid >> 7, k = (bid >> 1) & 63, ih = bid & 1;
    const int t = threadIdx.x;
    const int ti = t >> 4, tj = t & 15;

    for (int s = t; s < 432; s += 128) {
        int wb = s / 144, jj = s % 144;
        int wk = (wb == 0) ? k : (wb == 1) ? ((k + 63) & 63) : ((k + 1) & 63);
        sidx[s] = idxb[n * L_ + wk * WIN + jj];
    }
    __syncthreads();
    for (int s = t; s < 72 * 16; s += 128) {
        int rr = s >> 4, q4 = s & 15;
        int l = sidx[ih * 72 + rr];
        *(float4*)(sq + rr * 68 + q4 * 4) = *(const float4*)(xe + ((size_t)n * L_ + l) * 64 + q4 * 4);
    }
    float* outbase = raw + (size_t)(n * NWIN + k) * WIN * KJ + (size_t)ih * 72 * KJ;

    for (int wb = 0; wb < 3; wb++) {
        __syncthreads();
        for (int s = t; s < 144 * 16; s += 128) {
            int rr = s >> 4, q4 = s & 15;
            int l = sidx[wb * 144 + rr];
            float4 v = *(const float4*)(xe + ((size_t)n * L_ + l) * 64 + q4 * 4);
            float ss = v.x * v.x + v.y * v.y + v.z * v.z + v.w * v.w;
            ss += __shfl_xor(ss, 1); ss += __shfl_xor(ss, 2);
            ss += __shfl_xor(ss, 4); ss += __shfl_xor(ss, 8);
            float inv = 1.0f / fmaxf(sqrtf(ss), 5e-5f);
            v.x *= inv; v.y *= inv; v.z *= inv; v.w *= inv;
            *(float4*)(sk + rr * 68 + q4 * 4) = v;
        }
        __syncthreads();
        float acc[9][9];
#pragma unroll
        for (int a = 0; a < 9; a++)
#pragma unroll
            for (int b = 0; b < 9; b++) acc[a][b] = 0.f;
        for (int c4 = 0; c4 < 16; c4++) {
            float4 qv[9], kv[9];
#pragma unroll
            for (int a = 0; a < 9; a++) qv[a] = *(const float4*)(sq + (ti * 9 + a) * 68 + c4 * 4);
#pragma unroll
            for (int b = 0; b < 9; b++) kv[b] = *(const float4*)(sk + (tj * 9 + b) * 68 + c4 * 4);
#pragma unroll
            for (int a = 0; a < 9; a++)
#pragma unroll
                for (int b = 0; b < 9; b++)
                    acc[a][b] += qv[a].x * kv[b].x + qv[a].y * kv[b].y +
                                 qv[a].z * kv[b].z + qv[a].w * kv[b].w;
        }
        __syncthreads();      // done reading sk keys
#pragma unroll
        for (int a = 0; a < 9; a++)
#pragma unroll
            for (int b = 0; b < 9; b++)
                sk[(ti * 9 + a) * 144 + tj * 9 + b] = acc[a][b];
        __syncthreads();
        for (int s = t; s < 72 * 36; s += 128) {
            int i = s / 36, q = s % 36;
            *(float4*)(outbase + (size_t)i * KJ + wb * 144 + q * 4) =
                *(const float4*)(sk + i * 144 + q * 4);
        }
    }
}

// ---------------- row softmax in place + bs ----------------
__global__ __launch_bounds__(256) void k_softmax(float* __restrict__ score, float* __restrict__ bs) {
    const int row = blockIdx.x * 4 + (threadIdx.x >> 6);
    const int lane = threadIdx.x & 63;
    float* p = score + (size_t)row * KJ;
    float v[7];
    float m = -1e30f;
#pragma unroll
    for (int it = 0; it < 7; it++) {
        int j = lane + it * 64;
        v[it] = (j < KJ) ? p[j] : -1e30f;
        m = fmaxf(m, v[it]);
    }
#pragma unroll
    for (int o = 32; o >= 1; o >>= 1) m = fmaxf(m, __shfl_xor(m, o));
    float s = 0.f;
#pragma unroll
    for (int it = 0; it < 7; it++) {
        v[it] = __expf(v[it] - m);
        s += (lane + it * 64 < KJ) ? v[it] : 0.f;
    }
#pragma unroll
    for (int o = 32; o >= 1; o >>= 1) s += __shfl_xor(s, o);
    float inv = 1.f / s;
#pragma unroll
    for (int it = 0; it < 7; it++) {
        int j = lane + it * 64;
        if (j < KJ) p[j] = v[it] * inv;
    }
    if (lane == 0) bs[row] = m + logf(s);
}

// ---------------- PV: ret_sorted = score @ Y3 ----------------
// grid 2048 ((n*64+k)*4+cq4), block 256 (16 ti x 16 tj); thread 9i x 4c.
__global__ __launch_bounds__(256) void k_pv(const float* __restrict__ ye,
                                            const int* __restrict__ idxb,
                                            const float* __restrict__ score,
                                            float* __restrict__ ret) {
    __shared__ float ss[144 * 52];
    __shared__ float sy[48 * 68];
    __shared__ int sidx[432];
    const int bid = blockIdx.x;
    const int n = bid >> 8, k = (bid >> 2) & 63, cqb = (bid & 3) * 64;
    const int t = threadIdx.x;
    const int ti = t >> 4, tj = t & 15;

    for (int s = t; s < 432; s += 256) {
        int wb = s / 144, jj = s % 144;
        int wk = (wb == 0) ? k : (wb == 1) ? ((k + 63) & 63) : ((k + 1) & 63);
        sidx[s] = idxb[n * L_ + wk * WIN + jj];
    }
    float acc[9][4];
#pragma unroll
    for (int a = 0; a < 9; a++)
#pragma unroll
        for (int q = 0; q < 4; q++) acc[a][q] = 0.f;
    const float* srowbase = score + (size_t)(n * NWIN + k) * WIN * KJ;

    for (int jt = 0; jt < 9; jt++) {
        __syncthreads();
        for (int s = t; s < 144 * 48; s += 256) {
            int i = s / 48, jj = s % 48;
            ss[i * 52 + jj] = srowbase[(size_t)i * KJ + jt * 48 + jj];
        }
        for (int s = t; s < 48 * 16; s += 256) {
            int jj = s >> 4, q = s & 15;
            int l = sidx[jt * 48 + jj];
            *(float4*)(sy + jj * 68 + q * 4) =
                *(const float4*)(ye + ((size_t)n * L_ + l) * 256 + cqb + q * 4);
        }
        __syncthreads();
#pragma unroll 3
        for (int jg = 0; jg < 12; ++jg) {
            float4 y0 = *(const float4*)(sy + (jg * 4 + 0) * 68 + tj * 4);
            float4 y1 = *(const float4*)(sy + (jg * 4 + 1) * 68 + tj * 4);
            float4 y2 = *(const float4*)(sy + (jg * 4 + 2) * 68 + tj * 4);
            float4 y3 = *(const float4*)(sy + (jg * 4 + 3) * 68 + tj * 4);
#pragma unroll
            for (int a = 0; a < 9; ++a) {
                float4 sv = *(const float4*)(ss + (ti * 9 + a) * 52 + jg * 4);
                acc[a][0] += sv.x * y0.x + sv.y * y1.x + sv.z * y2.x + sv.w * y3.x;
                acc[a][1] += sv.x * y0.y + sv.y * y1.y + sv.z * y2.y + sv.w * y3.y;
                acc[a][2] += sv.x * y0.z + sv.y * y1.z + sv.z * y2.z + sv.w * y3.z;
                acc[a][3] += sv.x * y0.w + sv.y * y1.w + sv.z * y2.w + sv.w * y3.w;
            }
        }
    }
#pragma unroll
    for (int a = 0; a < 9; a++) {
        int i = ti * 9 + a;
        float4 o = {acc[a][0], acc[a][1], acc[a][2], acc[a][3]};
        *(float4*)(ret + ((size_t)n * L_ + (size_t)k * WIN + i) * 256 + cqb + tj * 4) = o;
    }
}

// ---------------- final scatter: out = x + 0.1 * ret[undo] ----------------
// grid 2304 (n*288+lt), block 256; 32 tokens per block.
__global__ __launch_bounds__(256) void k_out(const float* __restrict__ x,
                                             const float* __restrict__ ret,
                                             const int* __restrict__ undo,
                                             float* __restrict__ out) {
    __shared__ float sr[32 * 257];
    const int n = blockIdx.x / 288, lt = blockIdx.x % 288;
    const int lbase = lt * 32;
    const int t = threadIdx.x;
    for (int s = t; s < 32 * 64; s += 256) {
        int lr = s >> 6, q = s & 63;
        int p = undo[n * L_ + lbase + lr];
        *(float4*)(sr + lr * 257 + q * 4) = *(const float4*)(ret + ((size_t)n * L_ + p) * 256 + q * 4);
    }
    __syncthreads();
    const int lr = t & 31, cog = t >> 5;
    for (int cc = 0; cc < 32; cc++) {
        int co = cog * 32 + cc;
        size_t gi = ((size_t)(n * 256 + co)) * L_ + lbase + lr;
        out[gi] = x[gi] + 0.1f * sr[lr * 257 + co];
    }
}

extern "C" void kernel_launch(void* const* d_in, const int* in_sizes, int n_in,
                              void* d_out, int out_size, void* d_ws, size_t ws_size,
                              hipStream_t stream) {
    (void)in_sizes; (void)n_in; (void)out_size; (void)ws_size;
    const float* x     = (const float*)d_in[0];
    const float* means = (const float*)d_in[1];
    const float* wm    = (const float*)d_in[2];
    const float* bm    = (const float*)d_in[3];
    const float* wa    = (const float*)d_in[4];
    const float* ba    = (const float*)d_in[5];

    float* out   = (float*)d_out;
    float* score = out + (size_t)8 * 256 * L_;                 // 18,874,368
    float* bs    = score + (size_t)8 * NWIN * WIN * KJ;        // +31,850,496
    float* codesf = bs + (size_t)8 * L_;                       // +73,728

    float* xe  = (float*)d_ws;                                  // 4,718,592 f
    float* ye  = xe + (size_t)8 * L_ * 64;                      // 18,874,368 f
    float* ret = ye + (size_t)8 * L_ * 256;                     // 18,874,368 f
    float* wtr = ret + (size_t)8 * L_ * 256;                    // 147,456 f
    int* codes_i = (int*)(wtr + 147456);
    int* idxb    = codes_i + 8 * L_;
    int* undo    = idxb + 8 * L_;
    int* hist    = undo + 8 * L_;
    int* basebuf = hist + 8 * 36 * 128;

    k_wprep  <<<576, 256, 0, stream>>>(wm, wtr);
    k_conv3x3<<<1536, 128, 0, stream>>>(x, wtr, bm, xe);
    k_conv1x1<<<1152, 256, 0, stream>>>(x, wa, ba, ye);
    k_assign <<<288, 256, 0, stream>>>(xe, means, codes_i, codesf);
    k_hist   <<<288, 256, 0, stream>>>(codes_i, hist);
    k_scan   <<<8, 128, 0, stream>>>(hist, basebuf);
    k_rank   <<<288, 256, 0, stream>>>(codes_i, basebuf, idxb, undo);
    k_qk     <<<1024, 128, 0, stream>>>(xe, idxb, score);
    k_softmax<<<18432, 256, 0, stream>>>(score, bs);
    k_pv     <<<2048, 256, 0, stream>>>(ye, idxb, score, ret);
    k_out    <<<2304, 256, 0, stream>>>(x, ret, undo, out);
}

// Round 3
// 1239.212 us; speedup vs baseline: 1.1661x; 1.1073x over previous
//
#include <hip/hip_runtime.h>
#include <math.h>

#define L_    9216
#define WIN   144
#define NWIN  64
#define KJ    432

// ---------------- weight pre-transpose for conv3x3 ----------------
// wtr[(c*9+kk)*64 + cq] = wm[cq*2304 + c*9 + kk]
__global__ void k_wprep(const float* __restrict__ wm, float* __restrict__ wtr) {
    int s = blockIdx.x * 256 + threadIdx.x;       // 147456 total
    if (s < 147456) {
        int cq = s & 63, r = s >> 6;              // r = c*9+kk
        wtr[s] = wm[(size_t)cq * 2304 + r];
    }
}

// ---------------- conv3x3 v3: x[8,256,96,96] -> xe[8,9216,64] ----------------
// grid 768 (n*96+h), block 256 (4 waves; 8 wg x 32 cg); thread tile 12w x 2cq.
// 4 channels/iter, 64 iters, double-buffered LDS, float4 staging, 1 barrier/iter.
__global__ __launch_bounds__(256) void k_conv3x3(const float* __restrict__ x,
                                                 const float* __restrict__ wtr,
                                                 const float* __restrict__ bm,
                                                 float* __restrict__ xe) {
    __shared__ __align__(16) float sx[2][4][3][104];  // [buf][ch][row][idx], col = idx-1
    __shared__ __align__(16) float sw[2][4][9][64];   // [buf][ch][tap][cq]
    const int n = blockIdx.x / 96, h = blockIdx.x % 96;
    const int t = threadIdx.x;
    const int wg = t >> 5, cg = t & 31;
    const int w0 = wg * 12, cq0 = cg * 2;
    const float* xb = x + (size_t)n * 256 * 9216;

    // --- x staging descriptors: s in {t, t+256(<288)}; s -> ch=s/72, r=(s/24)%3, q=s%24
    const int ch0 = t / 72, r0 = (t / 24) % 3, q0 = t % 24;
    const int hh0 = h + r0 - 1;
    const bool v0 = (hh0 >= 0) && (hh0 < 96);
    const int off0 = ch0 * 9216 + (v0 ? hh0 : 0) * 96 + q0 * 4;
    const int s1 = t + 256;
    const bool has1 = (s1 < 288);
    const int ch1 = has1 ? s1 / 72 : 0, r1 = (s1 / 24) % 3, q1 = s1 % 24;
    const int hh1 = h + r1 - 1;
    const bool v1 = has1 && (hh1 >= 0) && (hh1 < 96);
    const int off1 = ch1 * 9216 + (v1 ? hh1 : 0) * 96 + q1 * 4;
    // --- w staging: s in {t, t+256, t+512(<576)}; s -> ch=s/144, kk=(s%144)/16, q4=s%16
    const int wch0 = t / 144, wkk0 = (t % 144) / 16, wq0 = t % 16;
    const int wch1 = (t + 256) / 144, wkk1 = ((t + 256) % 144) / 16, wq1 = (t + 256) % 16;
    const bool whas2 = (t + 512) < 576;
    const int wch2 = whas2 ? (t + 512) / 144 : 0, wkk2 = ((t + 512) % 144) / 16, wq2 = (t + 512) % 16;

    float acc[12][2];
#pragma unroll
    for (int j = 0; j < 12; ++j) { acc[j][0] = 0.f; acc[j][1] = 0.f; }

    float4 xr0, xr1, wr0, wr1, wr2;
#define C3_ISSUE(cb)                                                              \
    do {                                                                          \
        const float* xc = xb + (size_t)(cb) * 9216;                               \
        xr0 = v0 ? *(const float4*)(xc + off0) : float4{0.f, 0.f, 0.f, 0.f};      \
        xr1 = v1 ? *(const float4*)(xc + off1) : float4{0.f, 0.f, 0.f, 0.f};      \
        const float* wc = wtr + (size_t)(cb) * 576;                               \
        wr0 = *(const float4*)(wc + (wch0 * 9 + wkk0) * 64 + wq0 * 4);            \
        wr1 = *(const float4*)(wc + (wch1 * 9 + wkk1) * 64 + wq1 * 4);            \
        wr2 = whas2 ? *(const float4*)(wc + (wch2 * 9 + wkk2) * 64 + wq2 * 4)     \
                    : float4{0.f, 0.f, 0.f, 0.f};                                 \
    } while (0)
#define C3_COMMIT(buf)                                                            \
    do {                                                                          \
        float* d0 = &sx[buf][ch0][r0][q0 * 4 + 1];                                \
        d0[0] = xr0.x; d0[1] = xr0.y; d0[2] = xr0.z; d0[3] = xr0.w;               \
        if (has1) {                                                               \
            float* d1 = &sx[buf][ch1][r1][q1 * 4 + 1];                            \
            d1[0] = xr1.x; d1[1] = xr1.y; d1[2] = xr1.z; d1[3] = xr1.w;           \
        }                                                                         \
        *(float4*)&sw[buf][wch0][wkk0][wq0 * 4] = wr0;                            \
        *(float4*)&sw[buf][wch1][wkk1][wq1 * 4] = wr1;                            \
        if (whas2) *(float4*)&sw[buf][wch2][wkk2][wq2 * 4] = wr2;                 \
    } while (0)

    // zero edge columns (idx 0 and 97..103) once, both buffers
    if (t < 192) {
        int b = t / 96, ch = (t / 24) % 4, r = (t / 8) % 3, e = t % 8;
        int idx = (e == 0) ? 0 : 96 + e;
        sx[b][ch][r][idx] = 0.f;
    }
    C3_ISSUE(0);
    C3_COMMIT(0);
    __syncthreads();

    for (int it = 0; it < 64; ++it) {
        const int cur = it & 1;
        if (it < 63) C3_ISSUE((it + 1) * 4);
#pragma unroll
        for (int ch = 0; ch < 4; ++ch) {
            float2 wv[9];
#pragma unroll
            for (int tap = 0; tap < 9; ++tap)
                wv[tap] = *(const float2*)&sw[cur][ch][tap][cq0];
#pragma unroll
            for (int dh = 0; dh < 3; ++dh) {
                float xr[16];
#pragma unroll
                for (int q = 0; q < 4; ++q) {
                    float4 v = *(const float4*)&sx[cur][ch][dh][w0 + q * 4];
                    xr[q * 4 + 0] = v.x; xr[q * 4 + 1] = v.y;
                    xr[q * 4 + 2] = v.z; xr[q * 4 + 3] = v.w;
                }
#pragma unroll
                for (int kw = 0; kw < 3; ++kw) {
                    const float2 wk = wv[dh * 3 + kw];
#pragma unroll
                    for (int j = 0; j < 12; ++j) {
                        acc[j][0] += xr[j + kw] * wk.x;
                        acc[j][1] += xr[j + kw] * wk.y;
                    }
                }
            }
        }
        if (it < 63) C3_COMMIT(cur ^ 1);
        __syncthreads();
    }
#undef C3_ISSUE
#undef C3_COMMIT

    const float b0 = bm[cq0], b1 = bm[cq0 + 1];
#pragma unroll
    for (int j = 0; j < 12; ++j) {
        float2 o = {acc[j][0] + b0, acc[j][1] + b1};
        *(float2*)&xe[((size_t)n * L_ + (size_t)h * 96 + w0 + j) * 64 + cq0] = o;
    }
}

// ---------------- conv1x1: ye[8,9216,256] ----------------
// grid 1152 (n*144+lt), block 256; tile 64 l x 256 co; thread 8l x 8co.
__global__ __launch_bounds__(256) void k_conv1x1(const float* __restrict__ x,
                                                 const float* __restrict__ wa,
                                                 const float* __restrict__ ba,
                                                 float* __restrict__ ye) {
    __shared__ float sx[32 * 64];
    __shared__ float swt[32 * 260];
    const int n = blockIdx.x / 144, lt = blockIdx.x % 144;
    const int l0 = lt * 64;
    const int t = threadIdx.x;
    const int cg = t & 31, lg = t >> 5;   // co = cg*8.., l = lg*8..
    float acc[8][8];
#pragma unroll
    for (int li = 0; li < 8; li++)
#pragma unroll
        for (int ci = 0; ci < 8; ci++) acc[li][ci] = 0.f;

    for (int ct = 0; ct < 8; ct++) {
        __syncthreads();
        for (int s = t; s < 2048; s += 256) {
            int cc = s >> 6, ll = s & 63;
            sx[cc * 64 + ll] = x[((size_t)(n * 256) + ct * 32 + cc) * L_ + l0 + ll];
        }
        for (int s = t; s < 8192; s += 256) {
            int co = s >> 5, cc = s & 31;
            swt[cc * 260 + co] = wa[(size_t)co * 256 + ct * 32 + cc];
        }
        __syncthreads();
#pragma unroll 8
        for (int cc = 0; cc < 32; cc++) {
            float4 xa4 = *(const float4*)(sx + cc * 64 + lg * 8);
            float4 xb4 = *(const float4*)(sx + cc * 64 + lg * 8 + 4);
            float4 wa4 = *(const float4*)(swt + cc * 260 + cg * 8);
            float4 wb4 = *(const float4*)(swt + cc * 260 + cg * 8 + 4);
            float xs[8] = {xa4.x, xa4.y, xa4.z, xa4.w, xb4.x, xb4.y, xb4.z, xb4.w};
            float ws_[8] = {wa4.x, wa4.y, wa4.z, wa4.w, wb4.x, wb4.y, wb4.z, wb4.w};
#pragma unroll
            for (int li = 0; li < 8; li++)
#pragma unroll
                for (int ci = 0; ci < 8; ci++) acc[li][ci] += xs[li] * ws_[ci];
        }
    }
    float bias[8];
#pragma unroll
    for (int ci = 0; ci < 8; ci++) bias[ci] = ba[cg * 8 + ci];
#pragma unroll
    for (int li = 0; li < 8; li++) {
        int l = l0 + lg * 8 + li;
        float4 o0, o1;
        o0.x = acc[li][0] + bias[0]; o0.y = acc[li][1] + bias[1];
        o0.z = acc[li][2] + bias[2]; o0.w = acc[li][3] + bias[3];
        o1.x = acc[li][4] + bias[4]; o1.y = acc[li][5] + bias[5];
        o1.z = acc[li][6] + bias[6]; o1.w = acc[li][7] + bias[7];
        *(float4*)(ye + ((size_t)n * L_ + l) * 256 + cg * 8) = o0;
        *(float4*)(ye + ((size_t)n * L_ + l) * 256 + cg * 8 + 4) = o1;
    }
}

// ---------------- kmeans assign (fp64 dot; norm is argmax-invariant) ----------------
__global__ __launch_bounds__(256) void k_assign(const float* __restrict__ xe,
                                                const float* __restrict__ means,
                                                int* __restrict__ codes_i,
                                                float* __restrict__ codes_f) {
    __shared__ float sm[128 * 64];
    for (int s = threadIdx.x; s < 8192; s += 256) sm[s] = means[s];
    __syncthreads();
    const int g = blockIdx.x * 256 + threadIdx.x;
    const float* row = xe + (size_t)g * 64;
    float v[64];
#pragma unroll
    for (int c4 = 0; c4 < 16; c4++) {
        float4 t4 = *(const float4*)(row + c4 * 4);
        v[c4 * 4 + 0] = t4.x; v[c4 * 4 + 1] = t4.y; v[c4 * 4 + 2] = t4.z; v[c4 * 4 + 3] = t4.w;
    }
    int best = 0;
    double bd = -1e300;
    for (int cl = 0; cl < 128; cl++) {
        double d = 0.0;
#pragma unroll
        for (int c4 = 0; c4 < 16; c4++) {
            float4 m4 = *(const float4*)(sm + cl * 64 + c4 * 4);
            d += (double)v[c4 * 4 + 0] * (double)m4.x + (double)v[c4 * 4 + 1] * (double)m4.y +
                 (double)v[c4 * 4 + 2] * (double)m4.z + (double)v[c4 * 4 + 3] * (double)m4.w;
        }
        if (d > bd) { bd = d; best = cl; }
    }
    codes_i[g] = best;
    codes_f[g] = (float)best;
}

// ---------------- stable counting sort (matches jnp.argsort stable) ----------------
__global__ void k_hist(const int* __restrict__ codes_i, int* __restrict__ hist) {
    __shared__ int h[128];
    if (threadIdx.x < 128) h[threadIdx.x] = 0;
    __syncthreads();
    int n = blockIdx.x / 36, ch = blockIdx.x % 36;
    int c = codes_i[n * L_ + ch * 256 + threadIdx.x];
    atomicAdd(&h[c], 1);
    __syncthreads();
    if (threadIdx.x < 128) hist[(n * 36 + ch) * 128 + threadIdx.x] = h[threadIdx.x];
}

__global__ void k_scan(const int* __restrict__ hist, int* __restrict__ basebuf) {
    __shared__ int tot[128];
    __shared__ int binstart[128];
    int n = blockIdx.x, c = threadIdx.x;
    int run = 0;
    int local[36];
    for (int ch = 0; ch < 36; ch++) { local[ch] = run; run += hist[(n * 36 + ch) * 128 + c]; }
    tot[c] = run;
    __syncthreads();
    if (c == 0) {
        int s = 0;
        for (int b = 0; b < 128; b++) { binstart[b] = s; s += tot[b]; }
    }
    __syncthreads();
    int bs0 = binstart[c];
    for (int ch = 0; ch < 36; ch++) basebuf[(n * 36 + ch) * 128 + c] = bs0 + local[ch];
}

__global__ void k_rank(const int* __restrict__ codes_i, const int* __restrict__ basebuf,
                       int* __restrict__ idxb, int* __restrict__ undo) {
    __shared__ int sc[256];
    __shared__ int sb[128];
    int n = blockIdx.x / 36, ch = blockIdx.x % 36;
    int i = threadIdx.x;
    int l = ch * 256 + i;
    int c = codes_i[n * L_ + l];
    sc[i] = c;
    if (i < 128) sb[i] = basebuf[(n * 36 + ch) * 128 + i];
    __syncthreads();
    int r = 0;
    for (int j = 0; j < i; j++) r += (sc[j] == c);
    int pos = sb[c] + r;
    idxb[n * L_ + pos] = l;
    undo[n * L_ + l] = pos;
}

// ---------------- QK: raw logits -> score region ----------------
// grid 1024 ((n*64+k)*2+ih), block 128 (8 ti x 16 tj); thread 9x9 tile.
__global__ __launch_bounds__(128) void k_qk(const float* __restrict__ xe,
                                            const int* __restrict__ idxb,
                                            float* __restrict__ raw) {
    __shared__ float sq[72 * 68];
    __shared__ float sk[10368];     // 144 key rows @ stride 68; reused as 72x144 dump
    __shared__ int sidx[432];
    const int bid = blockIdx.x;
    const int n = bid >> 7, k = (bid >> 1) & 63, ih = bid & 1;
    const int t = threadIdx.x;
    const int ti = t >> 4, tj = t & 15;

    for (int s = t; s < 432; s += 128) {
        int wb = s / 144, jj = s % 144;
        int wk = (wb == 0) ? k : (wb == 1) ? ((k + 63) & 63) : ((k + 1) & 63);
        sidx[s] = idxb[n * L_ + wk * WIN + jj];
    }
    __syncthreads();
    for (int s = t; s < 72 * 16; s += 128) {
        int rr = s >> 4, q4 = s & 15;
        int l = sidx[ih * 72 + rr];
        *(float4*)(sq + rr * 68 + q4 * 4) = *(const float4*)(xe + ((size_t)n * L_ + l) * 64 + q4 * 4);
    }
    float* outbase = raw + (size_t)(n * NWIN + k) * WIN * KJ + (size_t)ih * 72 * KJ;

    for (int wb = 0; wb < 3; wb++) {
        __syncthreads();
        for (int s = t; s < 144 * 16; s += 128) {
            int rr = s >> 4, q4 = s & 15;
            int l = sidx[wb * 144 + rr];
            float4 v = *(const float4*)(xe + ((size_t)n * L_ + l) * 64 + q4 * 4);
            float ss = v.x * v.x + v.y * v.y + v.z * v.z + v.w * v.w;
            ss += __shfl_xor(ss, 1); ss += __shfl_xor(ss, 2);
            ss += __shfl_xor(ss, 4); ss += __shfl_xor(ss, 8);
            float inv = 1.0f / fmaxf(sqrtf(ss), 5e-5f);
            v.x *= inv; v.y *= inv; v.z *= inv; v.w *= inv;
            *(float4*)(sk + rr * 68 + q4 * 4) = v;
        }
        __syncthreads();
        float acc[9][9];
#pragma unroll
        for (int a = 0; a < 9; a++)
#pragma unroll
            for (int b = 0; b < 9; b++) acc[a][b] = 0.f;
        for (int c4 = 0; c4 < 16; c4++) {
            float4 qv[9], kv[9];
#pragma unroll
            for (int a = 0; a < 9; a++) qv[a] = *(const float4*)(sq + (ti * 9 + a) * 68 + c4 * 4);
#pragma unroll
            for (int b = 0; b < 9; b++) kv[b] = *(const float4*)(sk + (tj * 9 + b) * 68 + c4 * 4);
#pragma unroll
            for (int a = 0; a < 9; a++)
#pragma unroll
                for (int b = 0; b < 9; b++)
                    acc[a][b] += qv[a].x * kv[b].x + qv[a].y * kv[b].y +
                                 qv[a].z * kv[b].z + qv[a].w * kv[b].w;
        }
        __syncthreads();      // done reading sk keys
#pragma unroll
        for (int a = 0; a < 9; a++)
#pragma unroll
            for (int b = 0; b < 9; b++)
                sk[(ti * 9 + a) * 144 + tj * 9 + b] = acc[a][b];
        __syncthreads();
        for (int s = t; s < 72 * 36; s += 128) {
            int i = s / 36, q = s % 36;
            *(float4*)(outbase + (size_t)i * KJ + wb * 144 + q * 4) =
                *(const float4*)(sk + i * 144 + q * 4);
        }
    }
}

// ---------------- row softmax in place + bs ----------------
__global__ __launch_bounds__(256) void k_softmax(float* __restrict__ score, float* __restrict__ bs) {
    const int row = blockIdx.x * 4 + (threadIdx.x >> 6);
    const int lane = threadIdx.x & 63;
    float* p = score + (size_t)row * KJ;
    float v[7];
    float m = -1e30f;
#pragma unroll
    for (int it = 0; it < 7; it++) {
        int j = lane + it * 64;
        v[it] = (j < KJ) ? p[j] : -1e30f;
        m = fmaxf(m, v[it]);
    }
#pragma unroll
    for (int o = 32; o >= 1; o >>= 1) m = fmaxf(m, __shfl_xor(m, o));
    float s = 0.f;
#pragma unroll
    for (int it = 0; it < 7; it++) {
        v[it] = __expf(v[it] - m);
        s += (lane + it * 64 < KJ) ? v[it] : 0.f;
    }
#pragma unroll
    for (int o = 32; o >= 1; o >>= 1) s += __shfl_xor(s, o);
    float inv = 1.f / s;
#pragma unroll
    for (int it = 0; it < 7; it++) {
        int j = lane + it * 64;
        if (j < KJ) p[j] = v[it] * inv;
    }
    if (lane == 0) bs[row] = m + logf(s);
}

// ---------------- PV: ret_sorted = score @ Y3 ----------------
// grid 2048 ((n*64+k)*4+cq4), block 256 (16 ti x 16 tj); thread 9i x 4c.
__global__ __launch_bounds__(256) void k_pv(const float* __restrict__ ye,
                                            const int* __restrict__ idxb,
                                            const float* __restrict__ score,
                                            float* __restrict__ ret) {
    __shared__ float ss[144 * 52];
    __shared__ float sy[48 * 68];
    __shared__ int sidx[432];
    const int bid = blockIdx.x;
    const int n = bid >> 8, k = (bid >> 2) & 63, cqb = (bid & 3) * 64;
    const int t = threadIdx.x;
    const int ti = t >> 4, tj = t & 15;

    for (int s = t; s < 432; s += 256) {
        int wb = s / 144, jj = s % 144;
        int wk = (wb == 0) ? k : (wb == 1) ? ((k + 63) & 63) : ((k + 1) & 63);
        sidx[s] = idxb[n * L_ + wk * WIN + jj];
    }
    float acc[9][4];
#pragma unroll
    for (int a = 0; a < 9; a++)
#pragma unroll
        for (int q = 0; q < 4; q++) acc[a][q] = 0.f;
    const float* srowbase = score + (size_t)(n * NWIN + k) * WIN * KJ;

    for (int jt = 0; jt < 9; jt++) {
        __syncthreads();
        for (int s = t; s < 144 * 48; s += 256) {
            int i = s / 48, jj = s % 48;
            ss[i * 52 + jj] = srowbase[(size_t)i * KJ + jt * 48 + jj];
        }
        for (int s = t; s < 48 * 16; s += 256) {
            int jj = s >> 4, q = s & 15;
            int l = sidx[jt * 48 + jj];
            *(float4*)(sy + jj * 68 + q * 4) =
                *(const float4*)(ye + ((size_t)n * L_ + l) * 256 + cqb + q * 4);
        }
        __syncthreads();
#pragma unroll 3
        for (int jg = 0; jg < 12; ++jg) {
            float4 y0 = *(const float4*)(sy + (jg * 4 + 0) * 68 + tj * 4);
            float4 y1 = *(const float4*)(sy + (jg * 4 + 1) * 68 + tj * 4);
            float4 y2 = *(const float4*)(sy + (jg * 4 + 2) * 68 + tj * 4);
            float4 y3 = *(const float4*)(sy + (jg * 4 + 3) * 68 + tj * 4);
#pragma unroll
            for (int a = 0; a < 9; ++a) {
                float4 sv = *(const float4*)(ss + (ti * 9 + a) * 52 + jg * 4);
                acc[a][0] += sv.x * y0.x + sv.y * y1.x + sv.z * y2.x + sv.w * y3.x;
                acc[a][1] += sv.x * y0.y + sv.y * y1.y + sv.z * y2.y + sv.w * y3.y;
                acc[a][2] += sv.x * y0.z + sv.y * y1.z + sv.z * y2.z + sv.w * y3.z;
                acc[a][3] += sv.x * y0.w + sv.y * y1.w + sv.z * y2.w + sv.w * y3.w;
            }
        }
    }
#pragma unroll
    for (int a = 0; a < 9; a++) {
        int i = ti * 9 + a;
        float4 o = {acc[a][0], acc[a][1], acc[a][2], acc[a][3]};
        *(float4*)(ret + ((size_t)n * L_ + (size_t)k * WIN + i) * 256 + cqb + tj * 4) = o;
    }
}

// ---------------- final scatter: out = x + 0.1 * ret[undo] ----------------
// grid 2304 (n*288+lt), block 256; 32 tokens per block.
__global__ __launch_bounds__(256) void k_out(const float* __restrict__ x,
                                             const float* __restrict__ ret,
                                             const int* __restrict__ undo,
                                             float* __restrict__ out) {
    __shared__ float sr[32 * 257];
    const int n = blockIdx.x / 288, lt = blockIdx.x % 288;
    const int lbase = lt * 32;
    const int t = threadIdx.x;
    for (int s = t; s < 32 * 64; s += 256) {
        int lr = s >> 6, q = s & 63;
        int p = undo[n * L_ + lbase + lr];
        *(float4*)(sr + lr * 257 + q * 4) = *(const float4*)(ret + ((size_t)n * L_ + p) * 256 + q * 4);
    }
    __syncthreads();
    const int lr = t & 31, cog = t >> 5;
    for (int cc = 0; cc < 32; cc++) {
        int co = cog * 32 + cc;
        size_t gi = ((size_t)(n * 256 + co)) * L_ + lbase + lr;
        out[gi] = x[gi] + 0.1f * sr[lr * 257 + co];
    }
}

extern "C" void kernel_launch(void* const* d_in, const int* in_sizes, int n_in,
                              void* d_out, int out_size, void* d_ws, size_t ws_size,
                              hipStream_t stream) {
    (void)in_sizes; (void)n_in; (void)out_size; (void)ws_size;
    const float* x     = (const float*)d_in[0];
    const float* means = (const float*)d_in[1];
    const float* wm    = (const float*)d_in[2];
    const float* bm    = (const float*)d_in[3];
    const float* wa    = (const float*)d_in[4];
    const float* ba    = (const float*)d_in[5];

    float* out   = (float*)d_out;
    float* score = out + (size_t)8 * 256 * L_;                 // 18,874,368
    float* bs    = score + (size_t)8 * NWIN * WIN * KJ;        // +31,850,496
    float* codesf = bs + (size_t)8 * L_;                       // +73,728

    float* xe  = (float*)d_ws;                                  // 4,718,592 f
    float* ye  = xe + (size_t)8 * L_ * 64;                      // 18,874,368 f
    float* ret = ye + (size_t)8 * L_ * 256;                     // 18,874,368 f
    float* wtr = ret + (size_t)8 * L_ * 256;                    // 147,456 f
    int* codes_i = (int*)(wtr + 147456);
    int* idxb    = codes_i + 8 * L_;
    int* undo    = idxb + 8 * L_;
    int* hist    = undo + 8 * L_;
    int* basebuf = hist + 8 * 36 * 128;

    k_wprep  <<<576, 256, 0, stream>>>(wm, wtr);
    k_conv3x3<<<768, 256, 0, stream>>>(x, wtr, bm, xe);
    k_conv1x1<<<1152, 256, 0, stream>>>(x, wa, ba, ye);
    k_assign <<<288, 256, 0, stream>>>(xe, means, codes_i, codesf);
    k_hist   <<<288, 256, 0, stream>>>(codes_i, hist);
    k_scan   <<<8, 128, 0, stream>>>(hist, basebuf);
    k_rank   <<<288, 256, 0, stream>>>(codes_i, basebuf, idxb, undo);
    k_qk     <<<1024, 128, 0, stream>>>(xe, idxb, score);
    k_softmax<<<18432, 256, 0, stream>>>(score, bs);
    k_pv     <<<2048, 256, 0, stream>>>(ye, idxb, score, ret);
    k_out    <<<2304, 256, 0, stream>>>(x, ret, undo, out);
}

// Round 5
// 1134.096 us; speedup vs baseline: 1.2742x; 1.0927x over previous
//
#include <hip/hip_runtime.h>
#include <math.h>

#define L_    9216
#define WIN   144
#define NWIN  64
#define KJ    432

typedef __bf16 bf16x8 __attribute__((ext_vector_type(8)));
typedef unsigned short u16x8 __attribute__((ext_vector_type(8)));
typedef float f32x4 __attribute__((ext_vector_type(4)));

__device__ __forceinline__ unsigned short f2bf(float f) {
    unsigned int u = __builtin_bit_cast(unsigned int, f);
    u = (u + 0x7FFFu + ((u >> 16) & 1u)) >> 16;
    return (unsigned short)u;
}

// ---------------- weight pre-transpose for conv3x3 ----------------
__global__ void k_wprep(const float* __restrict__ wm, float* __restrict__ wtr) {
    int s = blockIdx.x * 256 + threadIdx.x;       // 147456 total
    if (s < 147456) {
        int cq = s & 63, r = s >> 6;              // r = c*9+kk
        wtr[s] = wm[(size_t)cq * 2304 + r];
    }
}

// ---------------- conv3x3 v4.1: x[8,256,96,96] -> xe[8,9216,64] ----------------
// grid 768 (n*96+h), block 128 (16 cg x 8 wg); thread tile 12w x 4cq.
// 4 ch/iter, double-buffered LDS, float4 staging, 1 barrier/iter.
// v4 bug fixed: edge-zero loop now covers all 192 slots with 128 threads.
__global__ __launch_bounds__(128) void k_conv3x3(const float* __restrict__ x,
                                                 const float* __restrict__ wtr,
                                                 const float* __restrict__ bm,
                                                 float* __restrict__ xe) {
    __shared__ __align__(16) float sx[2][4][3][104];  // col = idx-1
    __shared__ __align__(16) float sw[2][4][9][64];
    const int n = blockIdx.x / 96, h = blockIdx.x % 96;
    const int t = threadIdx.x;
    const int cg = t & 15, wg = t >> 4;
    const int w0 = wg * 12, cq0 = cg * 4;
    const float* xb = x + (size_t)n * 256 * 9216;

    // x staging slots: 288 f4 = 4ch x 3r x 24q ; slots {t, t+128, t+256 if t<32}
    const int xch0 = t / 72, xr0i = (t / 24) % 3, xq0 = t % 24;
    const int xhh0 = h + xr0i - 1;
    const bool xv0 = (xhh0 >= 0) && (xhh0 < 96);
    const int xoff0 = xch0 * 9216 + (xv0 ? xhh0 : 0) * 96 + xq0 * 4;
    const int s1 = t + 128;
    const int xch1 = s1 / 72, xr1i = (s1 / 24) % 3, xq1 = s1 % 24;
    const int xhh1 = h + xr1i - 1;
    const bool xv1 = (xhh1 >= 0) && (xhh1 < 96);
    const int xoff1 = xch1 * 9216 + (xv1 ? xhh1 : 0) * 96 + xq1 * 4;
    const int s2 = t + 256;
    const bool xhas2 = s2 < 288;
    const int xch2 = xhas2 ? s2 / 72 : 0, xr2i = (s2 / 24) % 3, xq2 = s2 % 24;
    const int xhh2 = h + xr2i - 1;
    const bool xv2 = xhas2 && (xhh2 >= 0) && (xhh2 < 96);
    const int xoff2 = xch2 * 9216 + (xv2 ? xhh2 : 0) * 96 + xq2 * 4;
    // w staging slots: 576 f4 = 4ch x 9kk x 16q; slots {t, +128, +256, +384, +512 if t<64}
    const int wch0 = t / 144,          wkk0 = (t % 144) / 16,          wq0 = t % 16;
    const int wch1 = (t + 128) / 144,  wkk1 = ((t + 128) % 144) / 16,  wq1 = (t + 128) % 16;
    const int wch2 = (t + 256) / 144,  wkk2 = ((t + 256) % 144) / 16,  wq2 = (t + 256) % 16;
    const int wch3 = (t + 384) / 144,  wkk3 = ((t + 384) % 144) / 16,  wq3 = (t + 384) % 16;
    const bool whas4 = (t + 512) < 576;
    const int wch4 = whas4 ? (t + 512) / 144 : 0, wkk4 = ((t + 512) % 144) / 16, wq4 = (t + 512) % 16;

    float acc[12][4];
#pragma unroll
    for (int j = 0; j < 12; ++j)
#pragma unroll
        for (int q = 0; q < 4; ++q) acc[j][q] = 0.f;

    float4 xg0, xg1, xg2, wg0, wg1, wg2, wg3, wg4;
    const float4 fz = {0.f, 0.f, 0.f, 0.f};
#define C3_ISSUE(cb)                                                              \
    do {                                                                          \
        const float* xc = xb + (size_t)(cb) * 9216;                               \
        xg0 = xv0 ? *(const float4*)(xc + xoff0) : fz;                            \
        xg1 = xv1 ? *(const float4*)(xc + xoff1) : fz;                            \
        xg2 = xv2 ? *(const float4*)(xc + xoff2) : fz;                            \
        const float* wc = wtr + (size_t)(cb) * 576;                               \
        wg0 = *(const float4*)(wc + (wch0 * 9 + wkk0) * 64 + wq0 * 4);            \
        wg1 = *(const float4*)(wc + (wch1 * 9 + wkk1) * 64 + wq1 * 4);            \
        wg2 = *(const float4*)(wc + (wch2 * 9 + wkk2) * 64 + wq2 * 4);            \
        wg3 = *(const float4*)(wc + (wch3 * 9 + wkk3) * 64 + wq3 * 4);            \
        wg4 = whas4 ? *(const float4*)(wc + (wch4 * 9 + wkk4) * 64 + wq4 * 4) : fz; \
    } while (0)
#define C3_COMMIT(buf)                                                            \
    do {                                                                          \
        float* d0 = &sx[buf][xch0][xr0i][xq0 * 4 + 1];                            \
        d0[0] = xg0.x; d0[1] = xg0.y; d0[2] = xg0.z; d0[3] = xg0.w;               \
        float* d1 = &sx[buf][xch1][xr1i][xq1 * 4 + 1];                            \
        d1[0] = xg1.x; d1[1] = xg1.y; d1[2] = xg1.z; d1[3] = xg1.w;               \
        if (xhas2) {                                                              \
            float* d2 = &sx[buf][xch2][xr2i][xq2 * 4 + 1];                        \
            d2[0] = xg2.x; d2[1] = xg2.y; d2[2] = xg2.z; d2[3] = xg2.w;           \
        }                                                                         \
        *(float4*)&sw[buf][wch0][wkk0][wq0 * 4] = wg0;                            \
        *(float4*)&sw[buf][wch1][wkk1][wq1 * 4] = wg1;                            \
        *(float4*)&sw[buf][wch2][wkk2][wq2 * 4] = wg2;                            \
        *(float4*)&sw[buf][wch3][wkk3][wq3 * 4] = wg3;                            \
        if (whas4) *(float4*)&sw[buf][wch4][wkk4][wq4 * 4] = wg4;                 \
    } while (0)

    // zero edge columns (idx 0 and 97..103), BOTH buffers: 192 slots, 128 threads
    for (int s = t; s < 192; s += 128) {
        int b = s / 96, rem = s % 96;
        int ch = rem / 24, rr = (rem / 8) % 3, e = rem % 8;
        int idx = (e == 0) ? 0 : 96 + e;
        sx[b][ch][rr][idx] = 0.f;
    }
    C3_ISSUE(0);
    C3_COMMIT(0);
    __syncthreads();

    for (int it = 0; it < 64; ++it) {
        const int cur = it & 1;
        if (it < 63) C3_ISSUE((it + 1) * 4);
#pragma unroll
        for (int ch = 0; ch < 4; ++ch) {
            float4 wv[9];
#pragma unroll
            for (int tap = 0; tap < 9; ++tap)
                wv[tap] = *(const float4*)&sw[cur][ch][tap][cq0];
#pragma unroll
            for (int dh = 0; dh < 3; ++dh) {
                float xr[16];
#pragma unroll
                for (int q = 0; q < 4; ++q) {
                    float4 v = *(const float4*)&sx[cur][ch][dh][w0 + q * 4];
                    xr[q * 4 + 0] = v.x; xr[q * 4 + 1] = v.y;
                    xr[q * 4 + 2] = v.z; xr[q * 4 + 3] = v.w;
                }
#pragma unroll
                for (int kw = 0; kw < 3; ++kw) {
                    const float4 wk = wv[dh * 3 + kw];
#pragma unroll
                    for (int j = 0; j < 12; ++j) {
                        acc[j][0] += xr[j + kw] * wk.x;
                        acc[j][1] += xr[j + kw] * wk.y;
                        acc[j][2] += xr[j + kw] * wk.z;
                        acc[j][3] += xr[j + kw] * wk.w;
                    }
                }
            }
        }
        if (it < 63) C3_COMMIT(cur ^ 1);
        __syncthreads();
    }
#undef C3_ISSUE
#undef C3_COMMIT

    const float4 bi = *(const float4*)(bm + cq0);
#pragma unroll
    for (int j = 0; j < 12; ++j) {
        float4 o = {acc[j][0] + bi.x, acc[j][1] + bi.y, acc[j][2] + bi.z, acc[j][3] + bi.w};
        *(float4*)&xe[((size_t)n * L_ + (size_t)h * 96 + w0 + j) * 64 + cq0] = o;
    }
}

// ---------------- conv1x1: ye[8,9216,256] ----------------
__global__ __launch_bounds__(256) void k_conv1x1(const float* __restrict__ x,
                                                 const float* __restrict__ wa,
                                                 const float* __restrict__ ba,
                                                 float* __restrict__ ye) {
    __shared__ float sx[32 * 64];
    __shared__ float swt[32 * 260];
    const int n = blockIdx.x / 144, lt = blockIdx.x % 144;
    const int l0 = lt * 64;
    const int t = threadIdx.x;
    const int cg = t & 31, lg = t >> 5;
    float acc[8][8];
#pragma unroll
    for (int li = 0; li < 8; li++)
#pragma unroll
        for (int ci = 0; ci < 8; ci++) acc[li][ci] = 0.f;

    for (int ct = 0; ct < 8; ct++) {
        __syncthreads();
        for (int s = t; s < 2048; s += 256) {
            int cc = s >> 6, ll = s & 63;
            sx[cc * 64 + ll] = x[((size_t)(n * 256) + ct * 32 + cc) * L_ + l0 + ll];
        }
        for (int s = t; s < 8192; s += 256) {
            int co = s >> 5, cc = s & 31;
            swt[cc * 260 + co] = wa[(size_t)co * 256 + ct * 32 + cc];
        }
        __syncthreads();
#pragma unroll 8
        for (int cc = 0; cc < 32; cc++) {
            float4 xa4 = *(const float4*)(sx + cc * 64 + lg * 8);
            float4 xb4 = *(const float4*)(sx + cc * 64 + lg * 8 + 4);
            float4 wa4 = *(const float4*)(swt + cc * 260 + cg * 8);
            float4 wb4 = *(const float4*)(swt + cc * 260 + cg * 8 + 4);
            float xs[8] = {xa4.x, xa4.y, xa4.z, xa4.w, xb4.x, xb4.y, xb4.z, xb4.w};
            float ws_[8] = {wa4.x, wa4.y, wa4.z, wa4.w, wb4.x, wb4.y, wb4.z, wb4.w};
#pragma unroll
            for (int li = 0; li < 8; li++)
#pragma unroll
                for (int ci = 0; ci < 8; ci++) acc[li][ci] += xs[li] * ws_[ci];
        }
    }
    float bias[8];
#pragma unroll
    for (int ci = 0; ci < 8; ci++) bias[ci] = ba[cg * 8 + ci];
#pragma unroll
    for (int li = 0; li < 8; li++) {
        int l = l0 + lg * 8 + li;
        float4 o0, o1;
        o0.x = acc[li][0] + bias[0]; o0.y = acc[li][1] + bias[1];
        o0.z = acc[li][2] + bias[2]; o0.w = acc[li][3] + bias[3];
        o1.x = acc[li][4] + bias[4]; o1.y = acc[li][5] + bias[5];
        o1.z = acc[li][6] + bias[6]; o1.w = acc[li][7] + bias[7];
        *(float4*)(ye + ((size_t)n * L_ + l) * 256 + cg * 8) = o0;
        *(float4*)(ye + ((size_t)n * L_ + l) * 256 + cg * 8 + 4) = o1;
    }
}

// ---------------- kmeans assign (fp64 dot; norm is argmax-invariant) ----------------
__global__ __launch_bounds__(256) void k_assign(const float* __restrict__ xe,
                                                const float* __restrict__ means,
                                                int* __restrict__ codes_i,
                                                float* __restrict__ codes_f) {
    __shared__ float sm[128 * 64];
    for (int s = threadIdx.x; s < 8192; s += 256) sm[s] = means[s];
    __syncthreads();
    const int g = blockIdx.x * 256 + threadIdx.x;
    const float* row = xe + (size_t)g * 64;
    float v[64];
#pragma unroll
    for (int c4 = 0; c4 < 16; c4++) {
        float4 t4 = *(const float4*)(row + c4 * 4);
        v[c4 * 4 + 0] = t4.x; v[c4 * 4 + 1] = t4.y; v[c4 * 4 + 2] = t4.z; v[c4 * 4 + 3] = t4.w;
    }
    int best = 0;
    double bd = -1e300;
    for (int cl = 0; cl < 128; cl++) {
        double d = 0.0;
#pragma unroll
        for (int c4 = 0; c4 < 16; c4++) {
            float4 m4 = *(const float4*)(sm + cl * 64 + c4 * 4);
            d += (double)v[c4 * 4 + 0] * (double)m4.x + (double)v[c4 * 4 + 1] * (double)m4.y +
                 (double)v[c4 * 4 + 2] * (double)m4.z + (double)v[c4 * 4 + 3] * (double)m4.w;
        }
        if (d > bd) { bd = d; best = cl; }
    }
    codes_i[g] = best;
    codes_f[g] = (float)best;
}

// ---------------- stable counting sort ----------------
__global__ void k_hist(const int* __restrict__ codes_i, int* __restrict__ hist) {
    __shared__ int h[128];
    if (threadIdx.x < 128) h[threadIdx.x] = 0;
    __syncthreads();
    int n = blockIdx.x / 36, ch = blockIdx.x % 36;
    int c = codes_i[n * L_ + ch * 256 + threadIdx.x];
    atomicAdd(&h[c], 1);
    __syncthreads();
    if (threadIdx.x < 128) hist[(n * 36 + ch) * 128 + threadIdx.x] = h[threadIdx.x];
}

__global__ void k_scan(const int* __restrict__ hist, int* __restrict__ basebuf) {
    __shared__ int tot[128];
    __shared__ int binstart[128];
    int n = blockIdx.x, c = threadIdx.x;
    int run = 0;
    int local[36];
    for (int ch = 0; ch < 36; ch++) { local[ch] = run; run += hist[(n * 36 + ch) * 128 + c]; }
    tot[c] = run;
    __syncthreads();
    if (c == 0) {
        int s = 0;
        for (int b = 0; b < 128; b++) { binstart[b] = s; s += tot[b]; }
    }
    __syncthreads();
    int bs0 = binstart[c];
    for (int ch = 0; ch < 36; ch++) basebuf[(n * 36 + ch) * 128 + c] = bs0 + local[ch];
}

__global__ void k_rank(const int* __restrict__ codes_i, const int* __restrict__ basebuf,
                       int* __restrict__ idxb, int* __restrict__ undo) {
    __shared__ int sc[256];
    __shared__ int sb[128];
    int n = blockIdx.x / 36, ch = blockIdx.x % 36;
    int i = threadIdx.x;
    int l = ch * 256 + i;
    int c = codes_i[n * L_ + l];
    sc[i] = c;
    if (i < 128) sb[i] = basebuf[(n * 36 + ch) * 128 + i];
    __syncthreads();
    int r = 0;
    for (int j = 0; j < i; j++) r += (sc[j] == c);
    int pos = sb[c] + r;
    idxb[n * L_ + pos] = l;
    undo[n * L_ + l] = pos;
}

// ---------------- QK: raw logits -> score region ----------------
__global__ __launch_bounds__(128) void k_qk(const float* __restrict__ xe,
                                            const int* __restrict__ idxb,
                                            float* __restrict__ raw) {
    __shared__ float sq[72 * 68];
    __shared__ float sk[10368];
    __shared__ int sidx[432];
    const int bid = blockIdx.x;
    const int n = bid >> 7, k = (bid >> 1) & 63, ih = bid & 1;
    const int t = threadIdx.x;
    const int ti = t >> 4, tj = t & 15;

    for (int s = t; s < 432; s += 128) {
        int wb = s / 144, jj = s % 144;
        int wk = (wb == 0) ? k : (wb == 1) ? ((k + 63) & 63) : ((k + 1) & 63);
        sidx[s] = idxb[n * L_ + wk * WIN + jj];
    }
    __syncthreads();
    for (int s = t; s < 72 * 16; s += 128) {
        int rr = s >> 4, q4 = s & 15;
        int l = sidx[ih * 72 + rr];
        *(float4*)(sq + rr * 68 + q4 * 4) = *(const float4*)(xe + ((size_t)n * L_ + l) * 64 + q4 * 4);
    }
    float* outbase = raw + (size_t)(n * NWIN + k) * WIN * KJ + (size_t)ih * 72 * KJ;

    for (int wb = 0; wb < 3; wb++) {
        __syncthreads();
        for (int s = t; s < 144 * 16; s += 128) {
            int rr = s >> 4, q4 = s & 15;
            int l = sidx[wb * 144 + rr];
            float4 v = *(const float4*)(xe + ((size_t)n * L_ + l) * 64 + q4 * 4);
            float ss = v.x * v.x + v.y * v.y + v.z * v.z + v.w * v.w;
            ss += __shfl_xor(ss, 1); ss += __shfl_xor(ss, 2);
            ss += __shfl_xor(ss, 4); ss += __shfl_xor(ss, 8);
            float inv = 1.0f / fmaxf(sqrtf(ss), 5e-5f);
            v.x *= inv; v.y *= inv; v.z *= inv; v.w *= inv;
            *(float4*)(sk + rr * 68 + q4 * 4) = v;
        }
        __syncthreads();
        float acc[9][9];
#pragma unroll
        for (int a = 0; a < 9; a++)
#pragma unroll
            for (int b = 0; b < 9; b++) acc[a][b] = 0.f;
        for (int c4 = 0; c4 < 16; c4++) {
            float4 qv[9], kv[9];
#pragma unroll
            for (int a = 0; a < 9; a++) qv[a] = *(const float4*)(sq + (ti * 9 + a) * 68 + c4 * 4);
#pragma unroll
            for (int b = 0; b < 9; b++) kv[b] = *(const float4*)(sk + (tj * 9 + b) * 68 + c4 * 4);
#pragma unroll
            for (int a = 0; a < 9; a++)
#pragma unroll
                for (int b = 0; b < 9; b++)
                    acc[a][b] += qv[a].x * kv[b].x + qv[a].y * kv[b].y +
                                 qv[a].z * kv[b].z + qv[a].w * kv[b].w;
        }
        __syncthreads();
#pragma unroll
        for (int a = 0; a < 9; a++)
#pragma unroll
            for (int b = 0; b < 9; b++)
                sk[(ti * 9 + a) * 144 + tj * 9 + b] = acc[a][b];
        __syncthreads();
        for (int s = t; s < 72 * 36; s += 128) {
            int i = s / 36, q = s % 36;
            *(float4*)(outbase + (size_t)i * KJ + wb * 144 + q * 4) =
                *(const float4*)(sk + i * 144 + q * 4);
        }
    }
}

// ---------------- row softmax in place + bs ----------------
__global__ __launch_bounds__(256) void k_softmax(float* __restrict__ score, float* __restrict__ bs) {
    const int row = blockIdx.x * 4 + (threadIdx.x >> 6);
    const int lane = threadIdx.x & 63;
    float* p = score + (size_t)row * KJ;
    float v[7];
    float m = -1e30f;
#pragma unroll
    for (int it = 0; it < 7; it++) {
        int j = lane + it * 64;
        v[it] = (j < KJ) ? p[j] : -1e30f;
        m = fmaxf(m, v[it]);
    }
#pragma unroll
    for (int o = 32; o >= 1; o >>= 1) m = fmaxf(m, __shfl_xor(m, o));
    float s = 0.f;
#pragma unroll
    for (int it = 0; it < 7; it++) {
        v[it] = __expf(v[it] - m);
        s += (lane + it * 64 < KJ) ? v[it] : 0.f;
    }
#pragma unroll
    for (int o = 32; o >= 1; o >>= 1) s += __shfl_xor(s, o);
    float inv = 1.f / s;
#pragma unroll
    for (int it = 0; it < 7; it++) {
        int j = lane + it * 64;
        if (j < KJ) p[j] = v[it] * inv;
    }
    if (lane == 0) bs[row] = m + logf(s);
}

// ---------------- PV via bf16 MFMA: ret_sorted = score @ Y3 ----------------
// grid 512 (n*64+k), block 256 (4 waves); wave = N-quarter (64 co = 4 Ntiles),
// M = 144 (9 Mtiles), K = 432 pad 448, K-chunks of 64 staged to LDS as bf16.
__global__ __launch_bounds__(256) void k_pv_mfma(const float* __restrict__ ye,
                                                 const int* __restrict__ idxb,
                                                 const float* __restrict__ score,
                                                 float* __restrict__ ret) {
    __shared__ __align__(16) unsigned short pA[144 * 72];   // P[i][kk], stride 72
    __shared__ __align__(16) unsigned short pB[64 * 258];   // Y[kk][co], stride 258
    __shared__ int sidx[432];
    const int bid = blockIdx.x;
    const int n = bid >> 6, k = bid & 63;
    const int t = threadIdx.x, lane = t & 63, nq = t >> 6;

    for (int s = t; s < 432; s += 256) {
        int wb = s / 144, jj = s % 144;
        int wk = (wb == 0) ? k : (wb == 1) ? ((k + 63) & 63) : ((k + 1) & 63);
        sidx[s] = idxb[n * L_ + wk * WIN + jj];
    }

    f32x4 acc[9][4];
#pragma unroll
    for (int mt = 0; mt < 9; ++mt)
#pragma unroll
        for (int nt = 0; nt < 4; ++nt) {
            f32x4 z = {0.f, 0.f, 0.f, 0.f};
            acc[mt][nt] = z;
        }

    const float* srow = score + (size_t)(n * NWIN + k) * WIN * KJ;
    const float* yb = ye + (size_t)n * L_ * 256;
    const int aBase = (lane & 15) * 72 + (lane >> 4) * 8;
    const int bBase = (lane >> 4) * 8 * 258 + nq * 64 + (lane & 15);

    for (int kc = 0; kc < 7; ++kc) {
        __syncthreads();
        // stage P chunk [144 x 64] fp32 -> bf16
        for (int s = t; s < 2304; s += 256) {
            int i = s >> 4, c4 = s & 15;
            int kcol = kc * 64 + c4 * 4;
            float4 v = {0.f, 0.f, 0.f, 0.f};
            if (kcol < KJ) v = *(const float4*)(srow + (size_t)i * KJ + kcol);
            ushort4 b = {f2bf(v.x), f2bf(v.y), f2bf(v.z), f2bf(v.w)};
            *(ushort4*)&pA[i * 72 + c4 * 4] = b;
        }
        // stage Y chunk [64 x 256] gathered rows -> bf16
        for (int s = t; s < 4096; s += 256) {
            int j = s >> 6, c4g = s & 63;
            int kk = kc * 64 + j;
            float4 v = {0.f, 0.f, 0.f, 0.f};
            if (kk < KJ) v = *(const float4*)(yb + (size_t)sidx[kk] * 256 + c4g * 4);
            ushort2 b0 = {f2bf(v.x), f2bf(v.y)};
            ushort2 b1 = {f2bf(v.z), f2bf(v.w)};
            *(ushort2*)&pB[j * 258 + c4g * 4] = b0;
            *(ushort2*)&pB[j * 258 + c4g * 4 + 2] = b1;
        }
        __syncthreads();
#pragma unroll
        for (int ks = 0; ks < 2; ++ks) {
            bf16x8 af[9];
#pragma unroll
            for (int mt = 0; mt < 9; ++mt)
                af[mt] = *(const bf16x8*)&pA[aBase + mt * 1152 + ks * 32];
#pragma unroll
            for (int nt = 0; nt < 4; ++nt) {
                const int e = bBase + ks * 32 * 258 + nt * 16;
                u16x8 bu;
#pragma unroll
                for (int j = 0; j < 8; ++j) bu[j] = pB[e + j * 258];
                bf16x8 bf = __builtin_bit_cast(bf16x8, bu);
#pragma unroll
                for (int mt = 0; mt < 9; ++mt)
                    acc[mt][nt] = __builtin_amdgcn_mfma_f32_16x16x32_bf16(af[mt], bf, acc[mt][nt], 0, 0, 0);
            }
        }
    }
    float* rbase = ret + ((size_t)n * L_ + (size_t)k * WIN) * 256;
    const int rowb = (lane >> 4) * 4;
    const int colb = nq * 64 + (lane & 15);
#pragma unroll
    for (int mt = 0; mt < 9; ++mt)
#pragma unroll
        for (int nt = 0; nt < 4; ++nt)
#pragma unroll
            for (int r = 0; r < 4; ++r)
                rbase[(size_t)(mt * 16 + rowb + r) * 256 + colb + nt * 16] = acc[mt][nt][r];
}

// ---------------- final scatter: out = x + 0.1 * ret[undo] ----------------
__global__ __launch_bounds__(256) void k_out(const float* __restrict__ x,
                                             const float* __restrict__ ret,
                                             const int* __restrict__ undo,
                                             float* __restrict__ out) {
    __shared__ float sr[32 * 257];
    const int n = blockIdx.x / 288, lt = blockIdx.x % 288;
    const int lbase = lt * 32;
    const int t = threadIdx.x;
    for (int s = t; s < 32 * 64; s += 256) {
        int lr = s >> 6, q = s & 63;
        int p = undo[n * L_ + lbase + lr];
        *(float4*)(sr + lr * 257 + q * 4) = *(const float4*)(ret + ((size_t)n * L_ + p) * 256 + q * 4);
    }
    __syncthreads();
    const int lr = t & 31, cog = t >> 5;
    for (int cc = 0; cc < 32; cc++) {
        int co = cog * 32 + cc;
        size_t gi = ((size_t)(n * 256 + co)) * L_ + lbase + lr;
        out[gi] = x[gi] + 0.1f * sr[lr * 257 + co];
    }
}

extern "C" void kernel_launch(void* const* d_in, const int* in_sizes, int n_in,
                              void* d_out, int out_size, void* d_ws, size_t ws_size,
                              hipStream_t stream) {
    (void)in_sizes; (void)n_in; (void)out_size; (void)ws_size;
    const float* x     = (const float*)d_in[0];
    const float* means = (const float*)d_in[1];
    const float* wm    = (const float*)d_in[2];
    const float* bm    = (const float*)d_in[3];
    const float* wa    = (const float*)d_in[4];
    const float* ba    = (const float*)d_in[5];

    float* out   = (float*)d_out;
    float* score = out + (size_t)8 * 256 * L_;
    float* bs    = score + (size_t)8 * NWIN * WIN * KJ;
    float* codesf = bs + (size_t)8 * L_;

    float* xe  = (float*)d_ws;
    float* ye  = xe + (size_t)8 * L_ * 64;
    float* ret = ye + (size_t)8 * L_ * 256;
    float* wtr = ret + (size_t)8 * L_ * 256;
    int* codes_i = (int*)(wtr + 147456);
    int* idxb    = codes_i + 8 * L_;
    int* undo    = idxb + 8 * L_;
    int* hist    = undo + 8 * L_;
    int* basebuf = hist + 8 * 36 * 128;

    k_wprep  <<<576, 256, 0, stream>>>(wm, wtr);
    k_conv3x3<<<768, 128, 0, stream>>>(x, wtr, bm, xe);
    k_conv1x1<<<1152, 256, 0, stream>>>(x, wa, ba, ye);
    k_assign <<<288, 256, 0, stream>>>(xe, means, codes_i, codesf);
    k_hist   <<<288, 256, 0, stream>>>(codes_i, hist);
    k_scan   <<<8, 128, 0, stream>>>(hist, basebuf);
    k_rank   <<<288, 256, 0, stream>>>(codes_i, basebuf, idxb, undo);
    k_qk     <<<1024, 128, 0, stream>>>(xe, idxb, score);
    k_softmax<<<18432, 256, 0, stream>>>(score, bs);
    k_pv_mfma<<<512, 256, 0, stream>>>(ye, idxb, score, ret);
    k_out    <<<2304, 256, 0, stream>>>(x, ret, undo, out);
}